// Round 1
// baseline (712.538 us; speedup 1.0000x reference)
//
#include <hip/hip_runtime.h>
#include <stdint.h>

#define NXR 8192      // rows of X / Gram
#define NQR 8192      // query rows
#define DMEAN 64
#define DVAR 96
#define DYC 32

typedef float f32x4 __attribute__((ext_vector_type(4)));
typedef __bf16 bf16x8 __attribute__((ext_vector_type(8)));
typedef unsigned short us4v __attribute__((ext_vector_type(4)));

__device__ __forceinline__ unsigned short f2bf(float f) {
    union { float f; uint32_t u; } v; v.f = f;
    uint32_t r = (v.u + 0x7FFFu + ((v.u >> 16) & 1u)) >> 16;
    return (unsigned short)r;
}
__device__ __forceinline__ float bf2f(unsigned short b) {
    union { uint32_t u; float f; } v; v.u = ((uint32_t)b) << 16;
    return v.f;
}
// frag-order permutation for a [K x 32] matrix used as MFMA B operand:
// element (k, c) -> kb*1024 + (c>>4)*512 + lane*8 + j,
// lane = ((k>>3)&3)*16 + (c&15), j = k&7
__device__ __forceinline__ int perm_idx(int k, int c) {
    return (k >> 5) * 1024 + (c >> 4) * 512 +
           ((((k >> 3) & 3) * 16 + (c & 15)) * 8) + (k & 7);
}

// ---------------- K1: prep (concat, flip, norms, bf16 casts, zero, base out)
__global__ __launch_bounds__(256) void k_prep(
    const float* __restrict__ x_mu, const float* __restrict__ y_eta,
    const float* __restrict__ y_mean, const float* __restrict__ y_var,
    const float* __restrict__ X_mean, const float* __restrict__ X_var,
    const float* __restrict__ Z_mean, const float* __restrict__ Z_var,
    unsigned short* __restrict__ Qm, unsigned short* __restrict__ Qv,
    unsigned short* __restrict__ Xm, unsigned short* __restrict__ Xv,
    unsigned short* __restrict__ Zpm, unsigned short* __restrict__ Zpv,
    float* __restrict__ qn_m, float* __restrict__ qn_v,
    float* __restrict__ Xn_m, float* __restrict__ Xn_v,
    float* __restrict__ lam_f32, float* __restrict__ out)
{
    int tid = blockIdx.x * 256 + threadIdx.x;
    lam_f32[tid] = 0.0f;                       // 2048*256 == 2*8192*32 exactly
    int w = threadIdx.x >> 6;
    int lane = threadIdx.x & 63;
    int row = blockIdx.x * 4 + w;

    float accq_m = 0.f, accq_v = 0.f;
    if (lane < 32) {
        int c = lane;
        float xm = x_mu[row * 32 + c];
        float s  = y_mean[row * 32 + c] + y_var[row * 32 + c];
        float e  = 0.01f * y_eta[(NQR - 1 - row) * 32 + c];
        unsigned short bx = f2bf(xm), bs = f2bf(s), be = f2bf(e);
        Qm[row * DMEAN + c] = bx;  Qm[row * DMEAN + 32 + c] = bs;
        Qv[row * DVAR + c] = bx;   Qv[row * DVAR + 32 + c] = be;
        Qv[row * DVAR + 64 + c] = bs;
        out[row * 32 + c] = s;     // base: y_mean + y_var
        Zpm[perm_idx(row, c)] = f2bf(Z_mean[row * 32 + c]);
        Zpv[perm_idx(row, c)] = f2bf(Z_var[row * 32 + c]);
        float fx = bf2f(bx), fs = bf2f(bs), fe = bf2f(be);
        accq_m = fx * fx + fs * fs;
        accq_v = fx * fx + fe * fe + fs * fs;
    }
    // X side: norms from bf16-rounded values for d2 consistency
    float a = X_mean[row * DMEAN + lane];
    unsigned short ba = f2bf(a);
    Xm[row * DMEAN + lane] = ba;
    float fa = bf2f(ba);
    float accx_m = fa * fa;

    float b0 = X_var[row * DVAR + lane];
    unsigned short bb0 = f2bf(b0);
    Xv[row * DVAR + lane] = bb0;
    float fb0 = bf2f(bb0);
    float accx_v = fb0 * fb0;
    if (lane < 32) {
        float b1 = X_var[row * DVAR + 64 + lane];
        unsigned short bb1 = f2bf(b1);
        Xv[row * DVAR + 64 + lane] = bb1;
        float fb1 = bf2f(bb1);
        accx_v += fb1 * fb1;
    }
    for (int o = 32; o >= 1; o >>= 1) {
        accq_m += __shfl_xor(accq_m, o, 64);
        accq_v += __shfl_xor(accq_v, o, 64);
        accx_m += __shfl_xor(accx_m, o, 64);
        accx_v += __shfl_xor(accx_v, o, 64);
    }
    if (lane == 0) {
        qn_m[row] = accq_m; qn_v[row] = accq_v;
        Xn_m[row] = accx_m; Xn_v[row] = accx_v;
    }
}

// ---------------- K2: Lambda = kXX_inv @ Z  (bf16 MFMA, split-K=2, fp32 atomics)
__global__ __launch_bounds__(256) void k_lambda(
    const float* __restrict__ kXXm, const float* __restrict__ kXXv,
    const unsigned short* __restrict__ Zpm, const unsigned short* __restrict__ Zpv,
    float* __restrict__ lam_f32)
{
    int b = blockIdx.x;
    int mat = b & 1;
    int split = (b >> 1) & 1;
    int rb = b >> 2;                     // 0..127
    const float* A = mat ? kXXv : kXXm;
    const unsigned short* Zp = mat ? Zpv : Zpm;
    float* lam = lam_f32 + mat * (NXR * DYC);

    int w = threadIdx.x >> 6, lane = threadIdx.x & 63;
    int r0 = rb * 64 + w * 16;
    int arow = r0 + (lane & 15);
    int kgrp = (lane >> 4) * 8;
    const float* Arow = A + (size_t)arow * NXR;

    f32x4 acc0 = {0.f, 0.f, 0.f, 0.f}, acc1 = {0.f, 0.f, 0.f, 0.f};
#pragma unroll 2
    for (int kb = 0; kb < 128; ++kb) {
        int kbase = split * 4096 + kb * 32;
        int k = kbase + kgrp;
        const f32x4* p = (const f32x4*)(Arow + k);
        f32x4 a0 = p[0], a1 = p[1];
        union { unsigned short u[8]; bf16x8 v; } af;
#pragma unroll
        for (int j = 0; j < 4; ++j) { af.u[j] = f2bf(a0[j]); af.u[4 + j] = f2bf(a1[j]); }
        const unsigned short* zb = Zp + (size_t)(kbase >> 5) * 1024 + lane * 8;
        bf16x8 bz0 = *(const bf16x8*)(zb);
        bf16x8 bz1 = *(const bf16x8*)(zb + 512);
        acc0 = __builtin_amdgcn_mfma_f32_16x16x32_bf16(af.v, bz0, acc0, 0, 0, 0);
        acc1 = __builtin_amdgcn_mfma_f32_16x16x32_bf16(af.v, bz1, acc1, 0, 0, 0);
    }
    int rbase = r0 + (lane >> 4) * 4;
    int c0 = lane & 15;
#pragma unroll
    for (int r = 0; r < 4; ++r) {
        atomicAdd(&lam[(rbase + r) * DYC + c0], acc0[r]);
        atomicAdd(&lam[(rbase + r) * DYC + c0 + 16], acc1[r]);
    }
}

// ---------------- K2b: pack Lambda fp32 -> bf16 frag-order
__global__ __launch_bounds__(256) void k_pack(
    const float* __restrict__ lam_f32,
    unsigned short* __restrict__ Lpm, unsigned short* __restrict__ Lpv)
{
    int t = blockIdx.x * 256 + threadIdx.x;   // 0..524287
    int mat = t >> 18;
    int rem = t & 262143;
    int x = rem >> 5, c = rem & 31;
    unsigned short v = f2bf(lam_f32[t]);
    (mat ? Lpv : Lpm)[perm_idx(x, c)] = v;
}

// ---------------- K3: fused rbf + z = K^T @ Lambda (flash-style, no K matrix)
__global__ __launch_bounds__(256) void k_transport(
    const unsigned short* __restrict__ Qm, const unsigned short* __restrict__ Qv,
    const unsigned short* __restrict__ Xm, const unsigned short* __restrict__ Xv,
    const float* __restrict__ qn_m, const float* __restrict__ qn_v,
    const float* __restrict__ Xn_m, const float* __restrict__ Xn_v,
    const unsigned short* __restrict__ Lpm, const unsigned short* __restrict__ Lpv,
    float* __restrict__ out)
{
    __shared__ unsigned short KT[4][16 * 40];   // per-wave 16q x 32x tile, pitch 40
    int b = blockIdx.x;
    int mat = b & 1;
    int split = (b >> 1) & 3;
    int qb = b >> 3;                             // 0..127
    const unsigned short* Q = mat ? Qv : Qm;
    const unsigned short* X = mat ? Xv : Xm;
    const float* qn = mat ? qn_v : qn_m;
    const float* Xn = mat ? Xn_v : Xn_m;
    const unsigned short* Lp = mat ? Lpv : Lpm;
    const int D = mat ? DVAR : DMEAN;
    const int nk0 = mat ? 3 : 2;

    int w = threadIdx.x >> 6, lane = threadIdx.x & 63;
    int q0 = qb * 64 + w * 16;
    int qrow = q0 + (lane & 15);
    int g = lane >> 4;

    bf16x8 Qf[3];
    for (int c0 = 0; c0 < nk0; ++c0)
        Qf[c0] = *(const bf16x8*)(Q + (size_t)qrow * D + c0 * 32 + g * 8);
    float qn_c = qn[qrow];
    unsigned short* lds = KT[w];

    f32x4 z0 = {0.f, 0.f, 0.f, 0.f}, z1 = {0.f, 0.f, 0.f, 0.f};
    for (int xb = 0; xb < 64; ++xb) {
        int x0 = split * 2048 + xb * 32;
#pragma unroll
        for (int sub = 0; sub < 2; ++sub) {
            int xrow = x0 + sub * 16 + (lane & 15);
            const unsigned short* Xr = X + (size_t)xrow * D + g * 8;
            f32x4 s = {0.f, 0.f, 0.f, 0.f};
            s = __builtin_amdgcn_mfma_f32_16x16x32_bf16(*(const bf16x8*)(Xr), Qf[0], s, 0, 0, 0);
            s = __builtin_amdgcn_mfma_f32_16x16x32_bf16(*(const bf16x8*)(Xr + 32), Qf[1], s, 0, 0, 0);
            if (nk0 == 3)
                s = __builtin_amdgcn_mfma_f32_16x16x32_bf16(*(const bf16x8*)(Xr + 64), Qf[2], s, 0, 0, 0);
            int xnb = x0 + sub * 16 + g * 4;
            f32x4 xn4 = *(const f32x4*)(Xn + xnb);
            us4v kv;
#pragma unroll
            for (int r = 0; r < 4; ++r) {
                float d2 = xn4[r] + qn_c - 2.0f * s[r];
                d2 = fmaxf(d2, 0.0f);
                kv[r] = f2bf(__expf(-d2 * 0.0078125f));
            }
            // C-layout (col=q=lane&15, row=x_local) stored transposed: KT[q][x]
            *(us4v*)(lds + (lane & 15) * 40 + sub * 16 + g * 4) = kv;
        }
        // wave-private LDS: ensure the 64-lane writes completed before re-read
        asm volatile("s_waitcnt lgkmcnt(0)" ::: "memory");
        bf16x8 Kf = *(const bf16x8*)(lds + (lane & 15) * 40 + g * 8);  // A-frag KT[q][0..31]
        const unsigned short* lpb = Lp + (size_t)(x0 >> 5) * 1024 + lane * 8;
        bf16x8 l0 = *(const bf16x8*)(lpb);
        bf16x8 l1 = *(const bf16x8*)(lpb + 512);
        z0 = __builtin_amdgcn_mfma_f32_16x16x32_bf16(Kf, l0, z0, 0, 0, 0);
        z1 = __builtin_amdgcn_mfma_f32_16x16x32_bf16(Kf, l1, z1, 0, 0, 0);
    }
    int rbase = q0 + g * 4;
    int c0 = lane & 15;
#pragma unroll
    for (int r = 0; r < 4; ++r) {
        atomicAdd(&out[(rbase + r) * 32 + c0], z0[r]);
        atomicAdd(&out[(rbase + r) * 32 + c0 + 16], z1[r]);
    }
}

extern "C" void kernel_launch(void* const* d_in, const int* in_sizes, int n_in,
                              void* d_out, int out_size, void* d_ws, size_t ws_size,
                              hipStream_t stream) {
    const float* x_mu   = (const float*)d_in[0];
    const float* y_eta  = (const float*)d_in[1];
    const float* y_mean = (const float*)d_in[2];
    const float* y_var  = (const float*)d_in[3];
    const float* X_mean = (const float*)d_in[4];
    const float* X_var  = (const float*)d_in[5];
    const float* Z_mean = (const float*)d_in[6];
    const float* Z_var  = (const float*)d_in[7];
    const float* kXXm   = (const float*)d_in[8];
    const float* kXXv   = (const float*)d_in[9];
    float* out = (float*)d_out;

    char* ws = (char*)d_ws;
    size_t off = 0;
    auto carve = [&](size_t bytes) { char* p = ws + off; off += (bytes + 255) & ~(size_t)255; return p; };
    unsigned short* Qm  = (unsigned short*)carve(NQR * DMEAN * 2);
    unsigned short* Qv  = (unsigned short*)carve(NQR * DVAR * 2);
    unsigned short* Xm  = (unsigned short*)carve(NXR * DMEAN * 2);
    unsigned short* Xv  = (unsigned short*)carve(NXR * DVAR * 2);
    unsigned short* Zpm = (unsigned short*)carve(NXR * DYC * 2);
    unsigned short* Zpv = (unsigned short*)carve(NXR * DYC * 2);
    unsigned short* Lpm = (unsigned short*)carve(NXR * DYC * 2);
    unsigned short* Lpv = (unsigned short*)carve(NXR * DYC * 2);
    float* qn_m = (float*)carve(NQR * 4);
    float* qn_v = (float*)carve(NQR * 4);
    float* Xn_m = (float*)carve(NXR * 4);
    float* Xn_v = (float*)carve(NXR * 4);
    float* lam_f32 = (float*)carve(2 * NXR * DYC * 4);

    k_prep<<<dim3(2048), dim3(256), 0, stream>>>(
        x_mu, y_eta, y_mean, y_var, X_mean, X_var, Z_mean, Z_var,
        Qm, Qv, Xm, Xv, Zpm, Zpv, qn_m, qn_v, Xn_m, Xn_v, lam_f32, out);
    k_lambda<<<dim3(512), dim3(256), 0, stream>>>(kXXm, kXXv, Zpm, Zpv, lam_f32);
    k_pack<<<dim3(2048), dim3(256), 0, stream>>>(lam_f32, Lpm, Lpv);
    k_transport<<<dim3(1024), dim3(256), 0, stream>>>(
        Qm, Qv, Xm, Xv, qn_m, qn_v, Xn_m, Xn_v, Lpm, Lpv, out);
}